// Round 2
// baseline (4338.864 us; speedup 1.0000x reference)
//
#include <hip/hip_runtime.h>
#include <hip/hip_bf16.h>

// whole_network: attention -> corrcoef -> 5x (GCN + BatchNorm(node) + tanh) -> linear head
// B=8192, N=100, T=64. All inputs fp32; output fp32 [8192,2].
//
// Pipeline (batchnorm forces layer-sequential kernels):
//   KA  : per-b attention + corr (bf16 to HBM) + z1 = corr @ (x@W1^T) + b1  (+ stats L1)
//   KB_i: per-b  h = tanh(BN(z_i));  z_{i+1} = corr @ (h@W^T) + b  (+ stats L_{i+1})
//   KF  : h5 = tanh(BN(z5));  out = h5.flat @ Wf^T + bf
// Stats = per-node (sum, sumsq) over (batch, channel), fp32 atomics, memset each launch.

typedef unsigned int u32;

__device__ __forceinline__ float blo(u32 u) { return __uint_as_float(u << 16); }
__device__ __forceinline__ float bhi(u32 u) { return __uint_as_float(u & 0xffff0000u); }

// ---------------- KA LDS layout (bytes), total 75200 (2 blocks/CU) ----------------
// region0 [0..41600): xs f32[100][68] (P0-P1) -> A f32[100][104] (P2) -> corr f32[100][104] (P4-P5)
// V bf16[100][34] @41600, Q bf16[100][34] @48400, K bf16[100][34] @55200
// feat/chat f32[100][33] @48400 (over Q,K after S done), t0 f32[100][33] @62000
#define OFF_V  41600
#define OFF_Q  48400
#define OFF_K  55200
#define OFF_FE 48400
#define OFF_T0 62000
#define SMEM_KA 75200

__global__ __launch_bounds__(256, 2) void ka_kernel(
    const float* __restrict__ x,
    const float* __restrict__ Wq, const float* __restrict__ bq,
    const float* __restrict__ Wk, const float* __restrict__ bk,
    const float* __restrict__ Wv, const float* __restrict__ bv,
    const float* __restrict__ W1, const float* __restrict__ b1,
    __hip_bfloat16* __restrict__ corr_g,   // [B,100,100] bf16
    float* __restrict__ z1g,               // [B,100,32] f32
    float* __restrict__ stats1)            // [200]: sum[100], sumsq[100]
{
  __shared__ __align__(16) char smem[SMEM_KA];
  const int b   = blockIdx.x;
  const int tid = threadIdx.x;

  // ---- P0: load x -> xs f32 [100][68]
  {
    float4* xs4 = (float4*)smem;
    const float4* xg4 = (const float4*)(x + (size_t)b * 6400);
    for (int i4 = tid; i4 < 1600; i4 += 256) {
      int n = i4 >> 4, t4 = i4 & 15;
      xs4[n * 17 + t4] = xg4[i4];
    }
  }
  __syncthreads();

  // ---- P1: Q,K,V (bf16, +bias) and t0 = x@W1^T (f32, bias added at z1)
  {
    const int j = tid & 31, g = tid >> 5;
    float aq[13], ak[13], av[13], at[13];
#pragma unroll
    for (int k = 0; k < 13; ++k) { aq[k] = 0.f; ak[k] = 0.f; av[k] = 0.f; at[k] = 0.f; }
    const float4* Wq4 = (const float4*)Wq;
    const float4* Wk4 = (const float4*)Wk;
    const float4* Wv4 = (const float4*)Wv;
    const float4* W14 = (const float4*)W1;
    const float4* xs4 = (const float4*)smem;
#pragma unroll 4
    for (int t4 = 0; t4 < 16; ++t4) {
      float4 wqv = Wq4[(j << 4) | t4];
      float4 wkv = Wk4[(j << 4) | t4];
      float4 wvv = Wv4[(j << 4) | t4];
      float4 w1v = W14[(j << 4) | t4];
#pragma unroll
      for (int k = 0; k < 13; ++k) {
        float4 xv = xs4[(g + (k << 3)) * 17 + t4];   // rows >=100 read in-LDS garbage, masked at store
        aq[k] = fmaf(xv.x, wqv.x, fmaf(xv.y, wqv.y, fmaf(xv.z, wqv.z, fmaf(xv.w, wqv.w, aq[k]))));
        ak[k] = fmaf(xv.x, wkv.x, fmaf(xv.y, wkv.y, fmaf(xv.z, wkv.z, fmaf(xv.w, wkv.w, ak[k]))));
        av[k] = fmaf(xv.x, wvv.x, fmaf(xv.y, wvv.y, fmaf(xv.z, wvv.z, fmaf(xv.w, wvv.w, av[k]))));
        at[k] = fmaf(xv.x, w1v.x, fmaf(xv.y, w1v.y, fmaf(xv.z, w1v.z, fmaf(xv.w, w1v.w, at[k]))));
      }
    }
    __hip_bfloat16* Qb = (__hip_bfloat16*)(smem + OFF_Q);
    __hip_bfloat16* Kb = (__hip_bfloat16*)(smem + OFF_K);
    __hip_bfloat16* Vb = (__hip_bfloat16*)(smem + OFF_V);
    float* t0 = (float*)(smem + OFF_T0);
    float bqj = bq[j], bkj = bk[j], bvj = bv[j];
#pragma unroll
    for (int k = 0; k < 13; ++k) {
      int n = g + (k << 3);
      if (n < 100) {
        Qb[n * 34 + j] = __float2bfloat16(aq[k] + bqj);
        Kb[n * 34 + j] = __float2bfloat16(ak[k] + bkj);
        Vb[n * 34 + j] = __float2bfloat16(av[k] + bvj);
        t0[n * 33 + j] = at[k];
      }
    }
  }
  __syncthreads();

  // ---- P2a/b: S = Q@K^T (regs), softmax(S/32) in regs, write A f32[100][104] over xs
  {
    const int lane = tid & 63, wvid = tid >> 6;
    float s0a[25], s1a[25];
#pragma unroll
    for (int r = 0; r < 25; ++r) { s0a[r] = 0.f; s1a[r] = 0.f; }
    const u32* Qu  = (const u32*)(smem + OFF_Q);
    const u32* Ku0 = (const u32*)(smem + OFF_K) + lane * 17;
    const u32* Ku1 = Ku0 + 64 * 17;                 // cols 100..127 read garbage, masked
#pragma unroll 4
    for (int t2 = 0; t2 < 16; ++t2) {
      u32 k0 = Ku0[t2], k1 = Ku1[t2];
      float k0l = blo(k0), k0h = bhi(k0), k1l = blo(k1), k1h = bhi(k1);
#pragma unroll
      for (int r = 0; r < 25; ++r) {
        u32 qu = Qu[(wvid + (r << 2)) * 17 + t2];
        float ql = blo(qu), qh = bhi(qu);
        s0a[r] = fmaf(ql, k0l, fmaf(qh, k0h, s0a[r]));
        s1a[r] = fmaf(ql, k1l, fmaf(qh, k1h, s1a[r]));
      }
    }
    const bool m1ok = lane < 36;
    float* A = (float*)smem;
#pragma unroll
    for (int r = 0; r < 25; ++r) {
      int n = wvid + (r << 2);
      float s0 = s0a[r];
      float s1 = m1ok ? s1a[r] : -3.0e38f;
      float sm = fmaxf(s0, s1);
#pragma unroll
      for (int off = 32; off; off >>= 1) sm = fmaxf(sm, __shfl_xor(sm, off, 64));
      float e0 = __expf((s0 - sm) * 0.03125f);
      float e1 = m1ok ? __expf((s1 - sm) * 0.03125f) : 0.f;
      float sum = e0 + e1;
#pragma unroll
      for (int off = 32; off; off >>= 1) sum += __shfl_xor(sum, off, 64);
      float rr = 1.0f / sum;
      A[n * 104 + lane] = e0 * rr;
      if (m1ok) A[n * 104 + 64 + lane] = e1 * rr;
    }
  }
  __syncthreads();

  // ---- P2c: feat = A@V, then center+normalize rows -> chat (over Q,K region)
  {
    const int j = tid & 31, g = tid >> 5;
    float fa[13];
#pragma unroll
    for (int k = 0; k < 13; ++k) fa[k] = 0.f;
    const float4* A4 = (const float4*)smem;         // row stride 26 float4
    const __hip_bfloat16* Vb = (const __hip_bfloat16*)(smem + OFF_V);
#pragma unroll 5
    for (int m4 = 0; m4 < 25; ++m4) {
      float v0 = __bfloat162float(Vb[(m4 * 4 + 0) * 34 + j]);
      float v1 = __bfloat162float(Vb[(m4 * 4 + 1) * 34 + j]);
      float v2 = __bfloat162float(Vb[(m4 * 4 + 2) * 34 + j]);
      float v3 = __bfloat162float(Vb[(m4 * 4 + 3) * 34 + j]);
#pragma unroll
      for (int k = 0; k < 13; ++k) {
        float4 a = A4[(g + (k << 3)) * 26 + m4];
        fa[k] = fmaf(a.x, v0, fmaf(a.y, v1, fmaf(a.z, v2, fmaf(a.w, v3, fa[k]))));
      }
    }
    float* featL = (float*)(smem + OFF_FE);
#pragma unroll
    for (int k = 0; k < 13; ++k) {
      int n = g + (k << 3);
      float v = fa[k];
      float rs = v;
#pragma unroll
      for (int off = 16; off; off >>= 1) rs += __shfl_xor(rs, off, 32);
      float xc = v - rs * 0.03125f;                 // mean over 32 ch
      float s2 = xc * xc;
#pragma unroll
      for (int off = 16; off; off >>= 1) s2 += __shfl_xor(s2, off, 32);
      float inv = rsqrtf(s2);                       // corr = chat@chat^T (divisor cancels)
      if (n < 100) featL[n * 33 + j] = xc * inv;
    }
  }
  __syncthreads();

  // ---- P4: corr = clip(chat@chat^T) -> LDS (over A) + HBM bf16
  {
    const int lane = tid & 63, wvid = tid >> 6;
    float c0a[25], c1a[25];
#pragma unroll
    for (int r = 0; r < 25; ++r) { c0a[r] = 0.f; c1a[r] = 0.f; }
    const float* featL = (const float*)(smem + OFF_FE);
    const float* ca = featL + lane * 33;
    const float* cb = featL + (lane + 64) * 33;     // cols >=100 garbage, masked
#pragma unroll 4
    for (int t = 0; t < 32; ++t) {
      float a = ca[t], bb = cb[t];
#pragma unroll
      for (int r = 0; r < 25; ++r) {
        float q = featL[(wvid + (r << 2)) * 33 + t];
        c0a[r] = fmaf(q, a, c0a[r]);
        c1a[r] = fmaf(q, bb, c1a[r]);
      }
    }
    float* corrL = (float*)smem;
    __hip_bfloat16* cg = corr_g + (size_t)b * 10000;
    const bool mok = lane < 36;
#pragma unroll
    for (int r = 0; r < 25; ++r) {
      int n = wvid + (r << 2);
      float d0 = fminf(1.f, fmaxf(-1.f, c0a[r]));
      corrL[n * 104 + lane] = d0;
      cg[n * 100 + lane] = __float2bfloat16(d0);
      if (mok) {
        float d1 = fminf(1.f, fmaxf(-1.f, c1a[r]));
        corrL[n * 104 + 64 + lane] = d1;
        cg[n * 100 + 64 + lane] = __float2bfloat16(d1);
      }
    }
  }
  __syncthreads();

  // ---- P5: z1 = corr @ t0 + b1 -> HBM f32, + stats
  {
    const int j = tid & 31, g = tid >> 5;
    float acc[13];
    float bj = b1[j];
#pragma unroll
    for (int k = 0; k < 13; ++k) acc[k] = bj;
    const float4* c4 = (const float4*)smem;
    const float* t0 = (const float*)(smem + OFF_T0);
#pragma unroll 5
    for (int m4 = 0; m4 < 25; ++m4) {
      float ta = t0[(m4 * 4 + 0) * 33 + j];
      float tb = t0[(m4 * 4 + 1) * 33 + j];
      float tc = t0[(m4 * 4 + 2) * 33 + j];
      float td = t0[(m4 * 4 + 3) * 33 + j];
#pragma unroll
      for (int k = 0; k < 13; ++k) {
        float4 c = c4[(g + (k << 3)) * 26 + m4];
        acc[k] = fmaf(c.x, ta, fmaf(c.y, tb, fmaf(c.z, tc, fmaf(c.w, td, acc[k]))));
      }
    }
    float* zo = z1g + (size_t)b * 3200;
#pragma unroll
    for (int k = 0; k < 13; ++k) {
      int n = g + (k << 3);
      if (n < 100) {
        float v = acc[k];
        zo[n * 32 + j] = v;
        float s = v, ss = v * v;
#pragma unroll
        for (int off = 16; off; off >>= 1) {
          s  += __shfl_xor(s, off, 32);
          ss += __shfl_xor(ss, off, 32);
        }
        if (j == 0) {
          atomicAdd(&stats1[n], s);
          atomicAdd(&stats1[100 + n], ss);
        }
      }
    }
  }
}

// ---------------- KB: one GCN step ----------------
template<int FIN, int FOUT>
__global__ __launch_bounds__(256, 2) void kb_kernel(
    const float* __restrict__ zin,
    const __hip_bfloat16* __restrict__ corr_g,
    const float* __restrict__ W, const float* __restrict__ bias,
    const float* __restrict__ stats_in, float* __restrict__ stats_out,
    float* __restrict__ zout)
{
  constexpr int LOGF  = (FOUT == 16) ? 4 : (FOUT == 8) ? 3 : (FOUT == 4) ? 2 : 1;
  constexpr int LOGFI = (FIN == 32) ? 5 : (FIN == 16) ? 4 : (FIN == 8) ? 3 : 2;
  constexpr int RP = 256 / FOUT;
  constexpr int NR = (100 + RP - 1) / RP;

  __shared__ float mS[100], vS[100];
  __shared__ float hL[100 * 33];
  __shared__ float tL[100 * (FOUT + 1)];
  __shared__ __align__(16) float clL[100 * 104];

  const int b = blockIdx.x, tid = threadIdx.x;

  // corr: HBM bf16 -> LDS f32 (unpack once, coalesced reads)
  {
    const u32* cgu = (const u32*)(corr_g + (size_t)b * 10000);
    for (int u = tid; u < 5000; u += 256) {
      int n = (u * 5243) >> 18;           // u/50 for u<5000
      int mm = (u - n * 50) << 1;
      u32 cc = cgu[u];
      clL[n * 104 + mm]     = blo(cc);
      clL[n * 104 + mm + 1] = bhi(cc);
    }
  }
  if (tid < 100) {
    float cnt  = 8192.0f * (float)FIN;
    float mean = stats_in[tid] / cnt;
    float var  = stats_in[100 + tid] / cnt - mean * mean;
    mS[tid] = mean;
    vS[tid] = rsqrtf(var + 1e-5f);
  }
  __syncthreads();

  // h = tanh(BN(z))
  {
    const float4* zb4 = (const float4*)(zin + (size_t)b * 100 * FIN);
    for (int i4 = tid; i4 < 25 * FIN; i4 += 256) {
      int n = i4 >> (LOGFI - 2);
      int c = (i4 << 2) & (FIN - 1);
      float4 z = zb4[i4];
      float mn = mS[n], iv = vS[n];
      hL[n * 33 + c + 0] = tanhf((z.x - mn) * iv);
      hL[n * 33 + c + 1] = tanhf((z.y - mn) * iv);
      hL[n * 33 + c + 2] = tanhf((z.z - mn) * iv);
      hL[n * 33 + c + 3] = tanhf((z.w - mn) * iv);
    }
  }
  __syncthreads();

  const int j  = tid & (FOUT - 1);
  const int nb = tid >> LOGF;

  // t = h @ W^T
  {
    float wreg[FIN];
#pragma unroll
    for (int c = 0; c < FIN; ++c) wreg[c] = W[j * FIN + c];
#pragma unroll
    for (int k = 0; k < NR; ++k) {
      int n = nb + k * RP;
      if (n < 100) {
        float a = 0.f;
#pragma unroll
        for (int c = 0; c < FIN; ++c) a = fmaf(hL[n * 33 + c], wreg[c], a);
        tL[n * (FOUT + 1) + j] = a;
      }
    }
  }
  __syncthreads();

  // z = corr @ t + bias ; stats for next layer
  {
    float acc[NR];
    float bj = bias[j];
#pragma unroll
    for (int k = 0; k < NR; ++k) acc[k] = bj;
    int nrow[NR];
#pragma unroll
    for (int k = 0; k < NR; ++k) nrow[k] = min(nb + k * RP, 99);  // clamp: dup row 99, masked at store
    const float4* c4 = (const float4*)clL;
#pragma unroll 5
    for (int m4 = 0; m4 < 25; ++m4) {
      float ta = tL[(m4 * 4 + 0) * (FOUT + 1) + j];
      float tb = tL[(m4 * 4 + 1) * (FOUT + 1) + j];
      float tc = tL[(m4 * 4 + 2) * (FOUT + 1) + j];
      float td = tL[(m4 * 4 + 3) * (FOUT + 1) + j];
#pragma unroll
      for (int k = 0; k < NR; ++k) {
        float4 c = c4[nrow[k] * 26 + m4];
        acc[k] = fmaf(c.x, ta, fmaf(c.y, tb, fmaf(c.z, tc, fmaf(c.w, td, acc[k]))));
      }
    }
    float* zo = zout + (size_t)b * 100 * FOUT;
#pragma unroll
    for (int k = 0; k < NR; ++k) {
      int n = nb + k * RP;
      if (n < 100) {
        float v = acc[k];
        zo[n * FOUT + j] = v;
        float s = v, ss = v * v;
#pragma unroll
        for (int off = FOUT >> 1; off; off >>= 1) {
          s  += __shfl_xor(s, off, FOUT);
          ss += __shfl_xor(ss, off, FOUT);
        }
        if (j == 0) {
          atomicAdd(&stats_out[n], s);
          atomicAdd(&stats_out[100 + n], ss);
        }
      }
    }
  }
}

// ---------------- KF: final BN+tanh + [200]->[2] head ----------------
__global__ __launch_bounds__(256) void kf_kernel(
    const float* __restrict__ z5, const float* __restrict__ stats5,
    const float* __restrict__ Wf, const float* __restrict__ bfv,
    float* __restrict__ out)
{
  __shared__ float mS[100], vS[100];
  const int tid = threadIdx.x;
  if (tid < 100) {
    float cnt  = 8192.0f * 2.0f;
    float mean = stats5[tid] / cnt;
    float var  = stats5[100 + tid] / cnt - mean * mean;
    mS[tid] = mean;
    vS[tid] = rsqrtf(var + 1e-5f);
  }
  __syncthreads();
  const int wvid = tid >> 6, lane = tid & 63;
  const int b = blockIdx.x * 4 + wvid;
  const float* zb = z5 + (size_t)b * 200;
  float a0 = 0.f, a1 = 0.f;
#pragma unroll
  for (int p = 0; p < 4; ++p) {
    int jj = lane + p * 64;
    if (jj < 200) {
      int n = jj >> 1;
      float hv = tanhf((zb[jj] - mS[n]) * vS[n]);
      a0 = fmaf(hv, Wf[jj], a0);
      a1 = fmaf(hv, Wf[200 + jj], a1);
    }
  }
#pragma unroll
  for (int off = 32; off; off >>= 1) {
    a0 += __shfl_xor(a0, off, 64);
    a1 += __shfl_xor(a1, off, 64);
  }
  if (lane == 0) {
    out[b * 2 + 0] = a0 + bfv[0];
    out[b * 2 + 1] = a1 + bfv[1];
  }
}

extern "C" void kernel_launch(void* const* d_in, const int* in_sizes, int n_in,
                              void* d_out, int out_size, void* d_ws, size_t ws_size,
                              hipStream_t stream)
{
  const float* x  = (const float*)d_in[0];
  const float* Wq = (const float*)d_in[1];
  const float* bq = (const float*)d_in[2];
  const float* Wk = (const float*)d_in[3];
  const float* bk = (const float*)d_in[4];
  const float* Wv = (const float*)d_in[5];
  const float* bv = (const float*)d_in[6];
  const float* W1 = (const float*)d_in[7];
  const float* b1 = (const float*)d_in[8];
  const float* W2 = (const float*)d_in[9];
  const float* b2 = (const float*)d_in[10];
  const float* W3 = (const float*)d_in[11];
  const float* b3 = (const float*)d_in[12];
  const float* W4 = (const float*)d_in[13];
  const float* b4 = (const float*)d_in[14];
  const float* W5 = (const float*)d_in[15];
  const float* b5 = (const float*)d_in[16];
  const float* Wf = (const float*)d_in[17];
  const float* bf = (const float*)d_in[18];
  float* out = (float*)d_out;

  char* ws = (char*)d_ws;
  // ws layout (bytes):
  //   corr bf16 [8192,100,100] : 0         .. 163,840,000
  //   zA   f32  [8192,100,32]  : 163840000 .. 268,697,600
  //   zB   f32  [8192,100,16]  : 268697600 .. 321,126,400
  //   stats f32 5*[200]        : 321126400 .. +4000
  const size_t NEED = 321130400ull;
  if (ws_size < NEED) return;  // undersized workspace: fail validation loudly, don't fault the GPU

  __hip_bfloat16* corr_g = (__hip_bfloat16*)ws;
  float* zA    = (float*)(ws + 163840000ull);
  float* zB    = (float*)(ws + 268697600ull);
  float* stats = (float*)(ws + 321126400ull);

  hipMemsetAsync(stats, 0, 5 * 200 * sizeof(float), stream);

  ka_kernel<<<8192, 256, 0, stream>>>(x, Wq, bq, Wk, bk, Wv, bv, W1, b1,
                                      corr_g, zA, stats);
  kb_kernel<32, 16><<<8192, 256, 0, stream>>>(zA, corr_g, W2, b2, stats,       stats + 200, zB);
  kb_kernel<16,  8><<<8192, 256, 0, stream>>>(zB, corr_g, W3, b3, stats + 200, stats + 400, zA);
  kb_kernel< 8,  4><<<8192, 256, 0, stream>>>(zA, corr_g, W4, b4, stats + 400, stats + 600, zB);
  kb_kernel< 4,  2><<<8192, 256, 0, stream>>>(zB, corr_g, W5, b5, stats + 600, stats + 800, zA);
  kf_kernel<<<2048, 256, 0, stream>>>(zA, stats + 800, Wf, bf, out);
}